// Round 1
// baseline (617.439 us; speedup 1.0000x reference)
//
#include <hip/hip_runtime.h>

// ---------------------------------------------------------------------------
// Attention_16698832847178: B=2,S=2048,D=2048,H=16,HD=128,L=10
// Pipeline: cast x -> bf16; transpose-cast weights; QKV bf16 MFMA GEMMs with
// fused RoPE epilogue; transpose V to (B,H,HD,S); flash attention (online
// softmax, MFMA 16x16x32); adapter (L=10) softmax-add fused with O cast;
// output-projection GEMM (fp32 out).
// ---------------------------------------------------------------------------

typedef unsigned short ushort_t;
typedef unsigned int uint32;
typedef __attribute__((ext_vector_type(8))) short bf16x8;   // 8 bf16 = 4 VGPRs
typedef __attribute__((ext_vector_type(4))) float f32x4;

__device__ __forceinline__ void async16(void* lds, const void* g) {
  // global -> LDS direct copy, 16B per lane; LDS dest = uniform base + lane*16
  __builtin_amdgcn_global_load_lds((const __attribute__((address_space(1))) void*)g,
                                   (__attribute__((address_space(3))) void*)lds,
                                   16, 0, 0);
}
__device__ __forceinline__ ushort_t f2bf(float f) {
  uint32 u = __float_as_uint(f);
  u += 0x7FFFu + ((u >> 16) & 1u);   // round-to-nearest-even
  return (ushort_t)(u >> 16);
}
__device__ __forceinline__ float bf2f(ushort_t b) {
  return __uint_as_float(((uint32)b) << 16);
}

// ---------------------------------------------------------------------------
// cast x (fp32) -> bf16, 8 elements/thread
__global__ __launch_bounds__(256) void cast_x_kernel(const float* __restrict__ x,
                                                     ushort_t* __restrict__ Xb) {
  size_t i = ((size_t)blockIdx.x * 256 + threadIdx.x) * 8;
  float4 a = *(const float4*)(x + i);
  float4 b = *(const float4*)(x + i + 4);
  uint4 o;
  o.x = (uint32)f2bf(a.x) | ((uint32)f2bf(a.y) << 16);
  o.y = (uint32)f2bf(a.z) | ((uint32)f2bf(a.w) << 16);
  o.z = (uint32)f2bf(b.x) | ((uint32)f2bf(b.y) << 16);
  o.w = (uint32)f2bf(b.z) | ((uint32)f2bf(b.w) << 16);
  *(uint4*)(Xb + i) = o;
}

// ---------------------------------------------------------------------------
// W[k][n] fp32 -> Wt[n][k] bf16 (64x64 tiles, fp32 LDS pad+1 -> conflict-free)
__global__ __launch_bounds__(256) void transpose_w_kernel(
    const float* __restrict__ w0, const float* __restrict__ w1,
    const float* __restrict__ w2, const float* __restrict__ w3,
    ushort_t* __restrict__ outBase) {
  const float* W = (blockIdx.z == 0) ? w0 : (blockIdx.z == 1) ? w1
                 : (blockIdx.z == 2) ? w2 : w3;
  ushort_t* Wt = outBase + (size_t)blockIdx.z * 4194304;  // 2048*2048
  __shared__ float L[64][65];
  int t = threadIdx.x, tc = t & 63, tr = t >> 6;
  int k0 = blockIdx.x * 64, n0 = blockIdx.y * 64;
  for (int i = 0; i < 16; ++i) {
    int r = i * 4 + tr;
    L[r][tc] = W[(size_t)(k0 + r) * 2048 + n0 + tc];
  }
  __syncthreads();
  for (int i = 0; i < 16; ++i) {
    int r = i * 4 + tr;
    Wt[(size_t)(n0 + r) * 2048 + k0 + tc] = f2bf(L[tc][r]);
  }
}

// ---------------------------------------------------------------------------
// Vb (B,S,H,HD) bf16 -> Vt (B,H,HD,S) bf16
__global__ __launch_bounds__(256) void transpose_v_kernel(
    const ushort_t* __restrict__ Vb, ushort_t* __restrict__ Vt) {
  __shared__ ushort_t L[64][65];
  int t = threadIdx.x, tc = t & 63, tr = t >> 6;
  int s0 = blockIdx.x * 64, d0 = blockIdx.y * 64;
  int bh = blockIdx.z, b = bh >> 4, h = bh & 15;
  for (int i = 0; i < 16; ++i) {
    int r = i * 4 + tr;
    L[r][tc] = Vb[((size_t)b * 2048 + s0 + r) * 2048 + h * 128 + d0 + tc];
  }
  __syncthreads();
  for (int i = 0; i < 16; ++i) {
    int r = i * 4 + tr;
    Vt[((size_t)bh * 128 + d0 + r) * 2048 + s0 + tc] = L[tc][r];
  }
}

// ---------------------------------------------------------------------------
// adapter projections: ak/av[l][n] = sum_k adapter[l][k] * W[k][n]  (fp32)
// grid (8 n-blocks, 16 k-slices, 2 {k,v}); partial sums via atomicAdd
__global__ __launch_bounds__(256) void adapter_kv_kernel(
    const float* __restrict__ adapter, const float* __restrict__ wk,
    const float* __restrict__ wv, float* __restrict__ ak, float* __restrict__ av) {
  const float* W = blockIdx.z ? wv : wk;
  float* out = blockIdx.z ? av : ak;
  __shared__ float As[10][128];
  int t = threadIdx.x;
  int k0 = blockIdx.y * 128;
  for (int i = t; i < 1280; i += 256)
    As[i >> 7][i & 127] = adapter[(size_t)(i >> 7) * 2048 + k0 + (i & 127)];
  __syncthreads();
  int n = blockIdx.x * 256 + t;
  float acc[10];
#pragma unroll
  for (int l = 0; l < 10; ++l) acc[l] = 0.f;
  for (int kk = 0; kk < 128; ++kk) {
    float wv_ = W[(size_t)(k0 + kk) * 2048 + n];
#pragma unroll
    for (int l = 0; l < 10; ++l) acc[l] += As[l][kk] * wv_;
  }
#pragma unroll
  for (int l = 0; l < 10; ++l) atomicAdd(&out[l * 2048 + n], acc[l]);
}

// ---------------------------------------------------------------------------
// GEMM: C[M,N] = A[M,K] x Bt[N,K]^T, bf16 inputs, fp32 accum.
// 128x128 tile, BK=64, 4 waves each 64x64 (4x4 of 16x16x32 MFMA).
// LDS rows are 8x16B chunks XOR-swizzled by (row&7): conflict-free reads,
// wave-contiguous global_load_lds staging.
// mode 0: fp32 out; mode 1: bf16 out + RoPE; mode 3: bf16 out plain.
__global__ __launch_bounds__(256) void gemm_kernel(
    const ushort_t* __restrict__ A, const ushort_t* __restrict__ Bt,
    void* __restrict__ out, int M, int N, int K, int mode,
    const float* __restrict__ fc, const float* __restrict__ fs) {
  __shared__ char ldsA[16384];
  __shared__ char ldsB[16384];
  const int tid = threadIdx.x;
  const int w = tid >> 6, lane = tid & 63, quad = lane >> 4, l15 = lane & 15;
  const int wm = (w >> 1) * 64, wn = (w & 1) * 64;
  const size_t bm0 = (size_t)blockIdx.y * 128, bn0 = (size_t)blockIdx.x * 128;

  f32x4 zero4 = {0.f, 0.f, 0.f, 0.f};
  f32x4 acc[4][4];
#pragma unroll
  for (int i = 0; i < 4; ++i)
#pragma unroll
    for (int j = 0; j < 4; ++j) acc[i][j] = zero4;

  const int rS = w * 32;
  const int rowOff = lane >> 3;
  const int cph = lane & 7;

  for (int kt = 0; kt < K; kt += 64) {
#pragma unroll
    for (int i = 0; i < 4; ++i) {
      int r0 = rS + i * 8;
      int row = r0 + rowOff;
      int cl = cph ^ (row & 7);
      async16(ldsA + r0 * 128, A + (bm0 + row) * (size_t)K + kt + cl * 8);
      async16(ldsB + r0 * 128, Bt + (bn0 + row) * (size_t)K + kt + cl * 8);
    }
    __syncthreads();
#pragma unroll
    for (int ks = 0; ks < 2; ++ks) {
      bf16x8 af[4], bfv[4];
      int ch = ks * 4 + quad;
#pragma unroll
      for (int tt = 0; tt < 4; ++tt) {
        int ra = wm + tt * 16 + l15;
        af[tt] = *(const bf16x8*)(ldsA + ra * 128 + ((ch ^ (ra & 7)) * 16));
        int rb = wn + tt * 16 + l15;
        bfv[tt] = *(const bf16x8*)(ldsB + rb * 128 + ((ch ^ (rb & 7)) * 16));
      }
#pragma unroll
      for (int i = 0; i < 4; ++i)
#pragma unroll
        for (int j = 0; j < 4; ++j)
          acc[i][j] = __builtin_amdgcn_mfma_f32_16x16x32_bf16(af[i], bfv[j], acc[i][j], 0, 0, 0);
    }
    __syncthreads();
  }

  // epilogue: C layout col=lane&15, row=quad*4+reg  [verified m89/m91]
  if (mode == 0) {
    float* of = (float*)out;
#pragma unroll
    for (int i = 0; i < 4; ++i)
#pragma unroll
      for (int r = 0; r < 4; ++r) {
        size_t m = bm0 + wm + i * 16 + quad * 4 + r;
#pragma unroll
        for (int j = 0; j < 4; ++j) {
          size_t n = bn0 + wn + j * 16 + l15;
          of[m * N + n] = acc[i][j][r];
        }
      }
  } else if (mode == 1) {
    ushort_t* ob = (ushort_t*)out;
#pragma unroll
    for (int i = 0; i < 4; ++i)
#pragma unroll
      for (int r = 0; r < 4; ++r) {
        size_t m = bm0 + wm + i * 16 + quad * 4 + r;
        int s = (int)(m & 2047);
#pragma unroll
        for (int j = 0; j < 4; ++j) {
          size_t n = bn0 + wn + j * 16 + l15;
          float v = acc[i][j][r];
          float v2 = __shfl_xor(v, 1, 64);  // RoPE pair partner (col n^1)
          int fi = ((int)n & 127) >> 1;
          float c = fc[s * 64 + fi], sn = fs[s * 64 + fi];
          float o = (lane & 1) ? (v2 * sn + v * c) : (v * c - v2 * sn);
          ob[m * N + n] = f2bf(o);
        }
      }
  } else {
    ushort_t* ob = (ushort_t*)out;
#pragma unroll
    for (int i = 0; i < 4; ++i)
#pragma unroll
      for (int r = 0; r < 4; ++r) {
        size_t m = bm0 + wm + i * 16 + quad * 4 + r;
#pragma unroll
        for (int j = 0; j < 4; ++j) {
          size_t n = bn0 + wn + j * 16 + l15;
          ob[m * N + n] = f2bf(acc[i][j][r]);
        }
      }
  }
}

// ---------------------------------------------------------------------------
// Flash attention, causal. Block = 128 q rows (4 waves x 32), k-tile = 64.
// LDS: K[64 tok][128 d] (16 chunks, swz ^(row&15)), V^T[128 d][64 tok]
// (8 chunks, swz ^(row&7)), P[128 q][64 kk] bf16 (swz ^(row&7)).
__global__ __launch_bounds__(256) void flash_kernel(
    const ushort_t* __restrict__ Qb, const ushort_t* __restrict__ Kb,
    const ushort_t* __restrict__ Vt, float* __restrict__ O) {
  __shared__ char ldsK[16384];
  __shared__ char ldsV[16384];
  __shared__ char ldsP[16384];
  const int tid = threadIdx.x;
  const int w = tid >> 6, lane = tid & 63, quad = lane >> 4, l15 = lane & 15;
  const int bx = blockIdx.x;
  const int qt = (bx & 1) ? (15 - (bx >> 1)) : (bx >> 1);  // heavy/light pairing
  const int h = blockIdx.y, b = blockIdx.z;
  const float scale = 0.08838834764831845f;  // 1/sqrt(128)

  // Q fragments in registers: 2 m-tiles x 4 d-steps
  bf16x8 qf[2][4];
#pragma unroll
  for (int mt = 0; mt < 2; ++mt) {
    size_t qrow = (size_t)qt * 128 + w * 32 + mt * 16 + l15;
    const ushort_t* base = Qb + ((size_t)b * 2048 + qrow) * 2048 + h * 128 + quad * 8;
#pragma unroll
    for (int ds = 0; ds < 4; ++ds) qf[mt][ds] = *(const bf16x8*)(base + ds * 32);
  }

  f32x4 zero4 = {0.f, 0.f, 0.f, 0.f};
  f32x4 oacc[2][8];
  float mrow[2][4], lrow[2][4];
#pragma unroll
  for (int mt = 0; mt < 2; ++mt) {
#pragma unroll
    for (int n8 = 0; n8 < 8; ++n8) oacc[mt][n8] = zero4;
#pragma unroll
    for (int r = 0; r < 4; ++r) { mrow[mt][r] = -1e30f; lrow[mt][r] = 0.f; }
  }

  const int ktmax = 2 * qt + 1;
  for (int kt = 0; kt <= ktmax; ++kt) {
    // stage K-tile (wave w: rows w*16..+15, 4 instrs x 4 rows)
#pragma unroll
    for (int i = 0; i < 4; ++i) {
      int r0 = w * 16 + i * 4;
      int row = r0 + (lane >> 4);
      int cl = (lane & 15) ^ (row & 15);
      async16(ldsK + r0 * 256,
              Kb + ((size_t)b * 2048 + kt * 64 + row) * 2048 + h * 128 + cl * 8);
    }
    // stage V^T-tile (wave w: d-rows w*32..+31, 4 instrs x 8 rows)
#pragma unroll
    for (int i = 0; i < 4; ++i) {
      int d0 = w * 32 + i * 8;
      int dr = d0 + (lane >> 3);
      int cl = (lane & 7) ^ (dr & 7);
      async16(ldsV + d0 * 128,
              Vt + ((size_t)(b * 16 + h) * 128 + dr) * 2048 + kt * 64 + cl * 8);
    }
    __syncthreads();

    // S = Q K^T
    f32x4 sacc[2][4];
#pragma unroll
    for (int mt = 0; mt < 2; ++mt)
#pragma unroll
      for (int nt = 0; nt < 4; ++nt) sacc[mt][nt] = zero4;
#pragma unroll
    for (int ds = 0; ds < 4; ++ds) {
      bf16x8 kf[4];
      int ch = ds * 4 + quad;
#pragma unroll
      for (int nt = 0; nt < 4; ++nt) {
        int row = nt * 16 + l15;
        kf[nt] = *(const bf16x8*)(ldsK + row * 256 + ((ch ^ (row & 15)) * 16));
      }
#pragma unroll
      for (int mt = 0; mt < 2; ++mt)
#pragma unroll
        for (int nt = 0; nt < 4; ++nt)
          sacc[mt][nt] = __builtin_amdgcn_mfma_f32_16x16x32_bf16(qf[mt][ds], kf[nt], sacc[mt][nt], 0, 0, 0);
    }

    // online softmax
    const bool domask = (kt >= 2 * qt);
#pragma unroll
    for (int mt = 0; mt < 2; ++mt) {
      float tmax[4] = {-1e30f, -1e30f, -1e30f, -1e30f};
      const int qbase = qt * 128 + w * 32 + mt * 16 + quad * 4;
#pragma unroll
      for (int nt = 0; nt < 4; ++nt) {
        int kg = kt * 64 + nt * 16 + l15;
#pragma unroll
        for (int r = 0; r < 4; ++r) {
          float s = sacc[mt][nt][r] * scale;
          if (domask && kg > qbase + r) s = -1e30f;
          sacc[mt][nt][r] = s;
          tmax[r] = fmaxf(tmax[r], s);
        }
      }
#pragma unroll
      for (int r = 0; r < 4; ++r) {
        float t = tmax[r];
        t = fmaxf(t, __shfl_xor(t, 1, 64));
        t = fmaxf(t, __shfl_xor(t, 2, 64));
        t = fmaxf(t, __shfl_xor(t, 4, 64));
        t = fmaxf(t, __shfl_xor(t, 8, 64));
        float mnew = fmaxf(mrow[mt][r], t);
        float alpha = __expf(mrow[mt][r] - mnew);
        mrow[mt][r] = mnew;
        lrow[mt][r] *= alpha;
#pragma unroll
        for (int n8 = 0; n8 < 8; ++n8) oacc[mt][n8][r] *= alpha;
        tmax[r] = mnew;
      }
      float tsum[4] = {0.f, 0.f, 0.f, 0.f};
#pragma unroll
      for (int nt = 0; nt < 4; ++nt)
#pragma unroll
        for (int r = 0; r < 4; ++r) {
          float p = __expf(sacc[mt][nt][r] - tmax[r]);
          sacc[mt][nt][r] = p;
          tsum[r] += p;
        }
#pragma unroll
      for (int r = 0; r < 4; ++r) {
        float t = tsum[r];
        t += __shfl_xor(t, 1, 64);
        t += __shfl_xor(t, 2, 64);
        t += __shfl_xor(t, 4, 64);
        t += __shfl_xor(t, 8, 64);
        lrow[mt][r] += t;
      }
      // P (C-layout) -> LDS (A-layout readable), bf16
#pragma unroll
      for (int nt = 0; nt < 4; ++nt) {
        int col = nt * 16 + l15;
#pragma unroll
        for (int r = 0; r < 4; ++r) {
          int prow = w * 32 + mt * 16 + quad * 4 + r;
          int addr = prow * 128 + (((col >> 3) ^ (prow & 7)) * 16) + (col & 7) * 2;
          *(ushort_t*)(ldsP + addr) = f2bf(sacc[mt][nt][r]);
        }
      }
    }

    // O += P V  (per-wave P region; same-wave LDS RAW handled by compiler)
#pragma unroll
    for (int ks = 0; ks < 2; ++ks) {
      int ch = ks * 4 + quad;
      bf16x8 pf[2];
#pragma unroll
      for (int mt = 0; mt < 2; ++mt) {
        int prow = w * 32 + mt * 16 + l15;
        pf[mt] = *(const bf16x8*)(ldsP + prow * 128 + ((ch ^ (prow & 7)) * 16));
      }
#pragma unroll
      for (int n8 = 0; n8 < 8; ++n8) {
        int dr = n8 * 16 + l15;
        bf16x8 vf = *(const bf16x8*)(ldsV + dr * 128 + ((ch ^ (dr & 7)) * 16));
#pragma unroll
        for (int mt = 0; mt < 2; ++mt)
          oacc[mt][n8] = __builtin_amdgcn_mfma_f32_16x16x32_bf16(pf[mt], vf, oacc[mt][n8], 0, 0, 0);
      }
    }
    __syncthreads();
  }

  // normalize + store O (B,S,H,HD) fp32
#pragma unroll
  for (int mt = 0; mt < 2; ++mt) {
    float rl[4];
#pragma unroll
    for (int r = 0; r < 4; ++r) rl[r] = 1.f / lrow[mt][r];
    size_t qb0 = (size_t)qt * 128 + w * 32 + mt * 16 + quad * 4;
#pragma unroll
    for (int n8 = 0; n8 < 8; ++n8) {
      size_t col = (size_t)h * 128 + n8 * 16 + l15;
#pragma unroll
      for (int r = 0; r < 4; ++r)
        O[((size_t)b * 2048 + qb0 + r) * 2048 + col] = oacc[mt][n8][r] * rl[r];
    }
  }
}

// ---------------------------------------------------------------------------
// adapter attention add + cast O fp32 -> bf16. One wave per (b,s,h).
__global__ __launch_bounds__(256) void adapter_add_kernel(
    const float* __restrict__ O, const ushort_t* __restrict__ Qb,
    const float* __restrict__ ak, const float* __restrict__ av,
    const float* __restrict__ gate, ushort_t* __restrict__ Ob) {
  const int w = threadIdx.x >> 6, lane = threadIdx.x & 63;
  const size_t idx = (size_t)blockIdx.x * 4 + w;   // (b*2048+s)*16 + h
  const int h = (int)(idx & 15);
  const size_t bs = idx >> 4;
  const size_t base = bs * 2048 + h * 128 + lane * 2;
  uint32 qraw = *(const uint32*)(Qb + base);
  float q0 = bf2f((ushort_t)(qraw & 0xFFFFu));
  float q1 = bf2f((ushort_t)(qraw >> 16));
  const float scale = 0.08838834764831845f;
  const int col = h * 128 + lane * 2;
  float sc[10];
#pragma unroll
  for (int l = 0; l < 10; ++l) {
    float2 a = *(const float2*)(ak + l * 2048 + col);
    float v = q0 * a.x + q1 * a.y;
    v += __shfl_xor(v, 32, 64);
    v += __shfl_xor(v, 16, 64);
    v += __shfl_xor(v, 8, 64);
    v += __shfl_xor(v, 4, 64);
    v += __shfl_xor(v, 2, 64);
    v += __shfl_xor(v, 1, 64);
    sc[l] = v * scale;
  }
  float mx = sc[0];
#pragma unroll
  for (int l = 1; l < 10; ++l) mx = fmaxf(mx, sc[l]);
  float e[10], sum = 0.f;
#pragma unroll
  for (int l = 0; l < 10; ++l) { e[l] = __expf(sc[l] - mx); sum += e[l]; }
  float g = gate[h] / sum;
  float o0 = 0.f, o1 = 0.f;
#pragma unroll
  for (int l = 0; l < 10; ++l) {
    float2 a = *(const float2*)(av + l * 2048 + col);
    o0 += e[l] * a.x;
    o1 += e[l] * a.y;
  }
  float r0 = O[base] + g * o0;
  float r1 = O[base + 1] + g * o1;
  *(uint32*)(Ob + base) = (uint32)f2bf(r0) | ((uint32)f2bf(r1) << 16);
}

// ---------------------------------------------------------------------------
extern "C" void kernel_launch(void* const* d_in, const int* in_sizes, int n_in,
                              void* d_out, int out_size, void* d_ws, size_t ws_size,
                              hipStream_t stream) {
  (void)in_sizes; (void)n_in; (void)out_size; (void)ws_size;
  const float* x       = (const float*)d_in[0];
  const float* wq      = (const float*)d_in[1];
  const float* wk      = (const float*)d_in[2];
  const float* wv      = (const float*)d_in[3];
  const float* wo      = (const float*)d_in[4];
  const float* adapter = (const float*)d_in[5];
  const float* gate    = (const float*)d_in[6];
  const float* fc      = (const float*)d_in[7];
  const float* fs      = (const float*)d_in[8];

  char* ws = (char*)d_ws;
  // workspace layout (134,381,568 bytes total)
  ushort_t* Xb  = (ushort_t*)(ws + 0);            // 16,777,216  (also reused as Ob)
  ushort_t* WtQ = (ushort_t*)(ws + 16777216);     // 8,388,608
  ushort_t* WtK = (ushort_t*)(ws + 25165824);
  ushort_t* WtV = (ushort_t*)(ws + 33554432);
  ushort_t* WtO = (ushort_t*)(ws + 41943040);
  ushort_t* Qb  = (ushort_t*)(ws + 50331648);     // 16,777,216
  ushort_t* Kb  = (ushort_t*)(ws + 67108864);     // 16,777,216
  ushort_t* Vt  = (ushort_t*)(ws + 83886080);     // 16,777,216
  float*    O   = (float*)   (ws + 100663296);    // 33,554,432
  ushort_t* Vb  = (ushort_t*)(ws + 100663296);    // temp (first half of O region)
  float*    ak  = (float*)   (ws + 134217728);    // 81,920
  float*    av  = (float*)   (ws + 134299648);    // 81,920
  ushort_t* Ob  = Xb;                             // reuse: Xb dead after V GEMM

  cast_x_kernel<<<4096, 256, 0, stream>>>(x, Xb);
  transpose_w_kernel<<<dim3(32, 32, 4), 256, 0, stream>>>(wq, wk, wv, wo, WtQ);
  hipMemsetAsync(ak, 0, 163840, stream);
  adapter_kv_kernel<<<dim3(8, 16, 2), 256, 0, stream>>>(adapter, wk, wv, ak, av);
  // QKV projections (RoPE fused for Q,K)
  gemm_kernel<<<dim3(16, 32), 256, 0, stream>>>(Xb, WtQ, Qb, 4096, 2048, 2048, 1, fc, fs);
  gemm_kernel<<<dim3(16, 32), 256, 0, stream>>>(Xb, WtK, Kb, 4096, 2048, 2048, 1, fc, fs);
  gemm_kernel<<<dim3(16, 32), 256, 0, stream>>>(Xb, WtV, Vb, 4096, 2048, 2048, 3, fc, fs);
  transpose_v_kernel<<<dim3(32, 2, 32), 256, 0, stream>>>(Vb, Vt);
  flash_kernel<<<dim3(16, 16, 2), 256, 0, stream>>>(Qb, Kb, Vt, O);
  adapter_add_kernel<<<16384, 256, 0, stream>>>(O, Qb, ak, av, gate, Ob);
  // output projection -> d_out fp32
  gemm_kernel<<<dim3(16, 32), 256, 0, stream>>>(Ob, WtO, d_out, 4096, 2048, 2048, 0, fc, fs);
}